// Round 1
// baseline (2429.294 us; speedup 1.0000x reference)
//
#include <hip/hip_runtime.h>
#include <math.h>

#define S_LEN 4096
#define DM    1024
#define NHEAD 16
#define HDIM  64
#define C3    3072   // 3 * DM

// ---------------------------------------------------------------------------
// GEMM + bias: C[M,N] = A[M,K] @ B[K,N] + bias[N]
// A,B,C row-major fp32. BM=BN=128, BK=16, 256 threads, 8x8 microtile.
// Requires M%128==0, N%128==0, K%16==0.
// ---------------------------------------------------------------------------
__global__ __launch_bounds__(256)
void gemm_bias_f32(const float* __restrict__ A, const float* __restrict__ B,
                   const float* __restrict__ bias, float* __restrict__ C,
                   int M, int N, int K)
{
    __shared__ float As[16][132];   // transposed A tile: As[k][m], padded
    __shared__ float Bs[16][132];   // natural B tile: Bs[k][n], padded

    const int tid = threadIdx.x;
    const int tx  = tid & 15;       // output col group
    const int ty  = tid >> 4;       // output row group
    const int row0 = blockIdx.y * 128;
    const int col0 = blockIdx.x * 128;

    float acc[8][8];
    #pragma unroll
    for (int i = 0; i < 8; ++i)
        #pragma unroll
        for (int j = 0; j < 8; ++j) acc[i][j] = 0.f;

    const int lm  = tid >> 1;        // A tile row   0..127
    const int lk8 = (tid & 1) * 8;   // A tile k off 0 or 8
    const int lkB = tid >> 4;        // B tile k row 0..15
    const int lnB = (tid & 15) * 8;  // B tile col   0..120

    for (int k0 = 0; k0 < K; k0 += 16) {
        // stage A (transposed into LDS)
        const float* ap = A + (size_t)(row0 + lm) * K + k0 + lk8;
        float4 a0 = *(const float4*)ap;
        float4 a1 = *(const float4*)(ap + 4);
        As[lk8 + 0][lm] = a0.x; As[lk8 + 1][lm] = a0.y;
        As[lk8 + 2][lm] = a0.z; As[lk8 + 3][lm] = a0.w;
        As[lk8 + 4][lm] = a1.x; As[lk8 + 5][lm] = a1.y;
        As[lk8 + 6][lm] = a1.z; As[lk8 + 7][lm] = a1.w;
        // stage B (natural)
        const float* bp = B + (size_t)(k0 + lkB) * N + col0 + lnB;
        *(float4*)&Bs[lkB][lnB]     = *(const float4*)bp;
        *(float4*)&Bs[lkB][lnB + 4] = *(const float4*)(bp + 4);
        __syncthreads();

        #pragma unroll
        for (int k = 0; k < 16; ++k) {
            float4 va0 = *(float4*)&As[k][ty * 8];
            float4 va1 = *(float4*)&As[k][ty * 8 + 4];
            float4 vb0 = *(float4*)&Bs[k][tx * 8];
            float4 vb1 = *(float4*)&Bs[k][tx * 8 + 4];
            float av[8] = {va0.x, va0.y, va0.z, va0.w, va1.x, va1.y, va1.z, va1.w};
            float bv[8] = {vb0.x, vb0.y, vb0.z, vb0.w, vb1.x, vb1.y, vb1.z, vb1.w};
            #pragma unroll
            for (int i = 0; i < 8; ++i)
                #pragma unroll
                for (int j = 0; j < 8; ++j)
                    acc[i][j] = fmaf(av[i], bv[j], acc[i][j]);
        }
        __syncthreads();
    }

    // epilogue: add bias, vector stores
    #pragma unroll
    for (int i = 0; i < 8; ++i) {
        const int row = row0 + ty * 8 + i;
        float* cp = C + (size_t)row * N + col0 + tx * 8;
        const float* bb = bias + col0 + tx * 8;
        float4 o0 = {acc[i][0] + bb[0], acc[i][1] + bb[1],
                     acc[i][2] + bb[2], acc[i][3] + bb[3]};
        float4 o1 = {acc[i][4] + bb[4], acc[i][5] + bb[5],
                     acc[i][6] + bb[6], acc[i][7] + bb[7]};
        *(float4*)cp       = o0;
        *(float4*)(cp + 4) = o1;
    }
}

// ---------------------------------------------------------------------------
// Flash-style causal attention, fp32.
// qkv: [2*4096, 3072] where col = which*1024 + h*64 + d  (which: 0=Q,1=K,2=V)
// out: [2*4096, 1024] in [b, s, h, hd] layout (matches reference transpose).
// Block = (qt in 0..63, bh in 0..31), 256 threads, 64x64 tiles.
// Thread (ty,tx) owns a 4x4 sub-block: rows ty*4.., cols tx*4..
// ---------------------------------------------------------------------------
__global__ __launch_bounds__(256)
void attn_f32(const float* __restrict__ qkv, float* __restrict__ out)
{
    const int qt  = blockIdx.x;          // Q tile index (64 rows each)
    const int bh  = blockIdx.y;          // b*16 + h
    const int b   = bh >> 4;
    const int h   = bh & 15;
    const int tid = threadIdx.x;
    const int tx  = tid & 15;
    const int ty  = tid >> 4;

    __shared__ float Qs[64][68];   // transposed: Qs[d][i]
    __shared__ float Ks[64][68];   // transposed: Ks[d][j]
    __shared__ float Ps[64][68];   // transposed: Ps[k][r]
    __shared__ float Vs[64][64];   // natural:    Vs[k][c]

    const float scale = 0.125f;    // 1/sqrt(64)
    const float NEG   = -1e30f;
    const float* base = qkv + (size_t)b * S_LEN * C3 + h * HDIM;

    // ---- load Q tile (transposed) ----
    {
        const int i  = tid >> 2;          // row in tile 0..63
        const int d0 = (tid & 3) * 16;    // d offset
        const float* qp = base + (size_t)(qt * 64 + i) * C3 + d0;
        #pragma unroll
        for (int dd = 0; dd < 16; dd += 4) {
            float4 v = *(const float4*)(qp + dd);
            Qs[d0 + dd + 0][i] = v.x;
            Qs[d0 + dd + 1][i] = v.y;
            Qs[d0 + dd + 2][i] = v.z;
            Qs[d0 + dd + 3][i] = v.w;
        }
    }

    float m_r[4], l_r[4], o[4][4];
    #pragma unroll
    for (int i = 0; i < 4; ++i) {
        m_r[i] = NEG; l_r[i] = 0.f;
        #pragma unroll
        for (int j = 0; j < 4; ++j) o[i][j] = 0.f;
    }

    for (int kt = 0; kt <= qt; ++kt) {
        __syncthreads();   // previous iteration done reading Ks/Vs/Ps; Qs ready
        // ---- load K (transposed) and V (natural) tiles ----
        {
            const int i  = tid >> 2;
            const int d0 = (tid & 3) * 16;
            const float* kp = base + (size_t)(kt * 64 + i) * C3 + 1024 + d0;
            #pragma unroll
            for (int dd = 0; dd < 16; dd += 4) {
                float4 v = *(const float4*)(kp + dd);
                Ks[d0 + dd + 0][i] = v.x;
                Ks[d0 + dd + 1][i] = v.y;
                Ks[d0 + dd + 2][i] = v.z;
                Ks[d0 + dd + 3][i] = v.w;
            }
            const float* vp = base + (size_t)(kt * 64 + i) * C3 + 2048 + d0;
            #pragma unroll
            for (int dd = 0; dd < 16; dd += 4)
                *(float4*)&Vs[i][d0 + dd] = *(const float4*)(vp + dd);
        }
        __syncthreads();

        // ---- S = Q K^T ----
        float s[4][4];
        #pragma unroll
        for (int i = 0; i < 4; ++i)
            #pragma unroll
            for (int j = 0; j < 4; ++j) s[i][j] = 0.f;

        #pragma unroll 8
        for (int d = 0; d < 64; ++d) {
            float4 va = *(float4*)&Qs[d][ty * 4];
            float4 vb = *(float4*)&Ks[d][tx * 4];
            float av[4] = {va.x, va.y, va.z, va.w};
            float bv[4] = {vb.x, vb.y, vb.z, vb.w};
            #pragma unroll
            for (int i = 0; i < 4; ++i)
                #pragma unroll
                for (int j = 0; j < 4; ++j)
                    s[i][j] = fmaf(av[i], bv[j], s[i][j]);
        }

        // ---- scale + causal mask (only the diagonal tile needs masking) ----
        #pragma unroll
        for (int i = 0; i < 4; ++i)
            #pragma unroll
            for (int j = 0; j < 4; ++j) {
                s[i][j] *= scale;
                if (kt == qt && (tx * 4 + j) > (ty * 4 + i)) s[i][j] = NEG;
            }

        // ---- online softmax (rows are shared by the 16 tx lanes) ----
        float tmax[4];
        #pragma unroll
        for (int i = 0; i < 4; ++i)
            tmax[i] = fmaxf(fmaxf(s[i][0], s[i][1]), fmaxf(s[i][2], s[i][3]));
        #pragma unroll
        for (int off = 1; off < 16; off <<= 1)
            #pragma unroll
            for (int i = 0; i < 4; ++i)
                tmax[i] = fmaxf(tmax[i], __shfl_xor(tmax[i], off));

        float p[4][4], alpha[4], rsum[4];
        #pragma unroll
        for (int i = 0; i < 4; ++i) {
            const float nm = fmaxf(m_r[i], tmax[i]);
            alpha[i] = __expf(m_r[i] - nm);
            #pragma unroll
            for (int j = 0; j < 4; ++j) p[i][j] = __expf(s[i][j] - nm);
            m_r[i] = nm;
            rsum[i] = (p[i][0] + p[i][1]) + (p[i][2] + p[i][3]);
        }
        #pragma unroll
        for (int off = 1; off < 16; off <<= 1)
            #pragma unroll
            for (int i = 0; i < 4; ++i)
                rsum[i] += __shfl_xor(rsum[i], off);
        #pragma unroll
        for (int i = 0; i < 4; ++i) {
            l_r[i] = alpha[i] * l_r[i] + rsum[i];
            #pragma unroll
            for (int j = 0; j < 4; ++j) o[i][j] *= alpha[i];
        }

        // ---- store P transposed: Ps[c][r] ----
        #pragma unroll
        for (int j = 0; j < 4; ++j) {
            float4 pv = {p[0][j], p[1][j], p[2][j], p[3][j]};
            *(float4*)&Ps[tx * 4 + j][ty * 4] = pv;
        }
        __syncthreads();

        // ---- O += P V ----
        #pragma unroll 8
        for (int k = 0; k < 64; ++k) {
            float4 va = *(float4*)&Ps[k][ty * 4];
            float4 vb = *(float4*)&Vs[k][tx * 4];
            float av[4] = {va.x, va.y, va.z, va.w};
            float bv[4] = {vb.x, vb.y, vb.z, vb.w};
            #pragma unroll
            for (int i = 0; i < 4; ++i)
                #pragma unroll
                for (int j = 0; j < 4; ++j)
                    o[i][j] = fmaf(av[i], bv[j], o[i][j]);
        }
    }

    // ---- epilogue: normalize and store to [b, s, h, hd] layout ----
    #pragma unroll
    for (int i = 0; i < 4; ++i) {
        const int row = qt * 64 + ty * 4 + i;
        const float inv = 1.f / l_r[i];
        float4 ov = {o[i][0] * inv, o[i][1] * inv, o[i][2] * inv, o[i][3] * inv};
        *(float4*)(out + (size_t)(b * S_LEN + row) * DM + h * HDIM + tx * 4) = ov;
    }
}

// ---------------------------------------------------------------------------
extern "C" void kernel_launch(void* const* d_in, const int* in_sizes, int n_in,
                              void* d_out, int out_size, void* d_ws, size_t ws_size,
                              hipStream_t stream)
{
    const float* x     = (const float*)d_in[0];   // [2, 4096, 1024]
    const float* w_qkv = (const float*)d_in[1];   // [1024, 3072]
    const float* b_qkv = (const float*)d_in[2];   // [3072]
    const float* w_out = (const float*)d_in[3];   // [1024, 1024]
    const float* b_out = (const float*)d_in[4];   // [1024]
    float* out = (float*)d_out;                   // [2, 4096, 1024]

    const int M = 2 * S_LEN;                      // 8192 tokens

    float* qkv  = (float*)d_ws;                   // [8192, 3072]  100.7 MB
    float* attn = qkv + (size_t)M * C3;           // [8192, 1024]   33.5 MB

    // 1) QKV projection: [8192,1024] @ [1024,3072] + b_qkv
    gemm_bias_f32<<<dim3(C3 / 128, M / 128), 256, 0, stream>>>(
        x, w_qkv, b_qkv, qkv, M, C3, DM);

    // 2) causal flash attention -> attn in [b, s, h, hd] layout
    attn_f32<<<dim3(S_LEN / 64, 2 * NHEAD), 256, 0, stream>>>(qkv, attn);

    // 3) output projection: [8192,1024] @ [1024,1024] + b_out
    gemm_bias_f32<<<dim3(DM / 128, M / 128), 256, 0, stream>>>(
        attn, w_out, b_out, out, M, DM, DM);
}

// Round 2
// 1189.966 us; speedup vs baseline: 2.0415x; 2.0415x over previous
//
#include <hip/hip_runtime.h>
#include <math.h>

#define S_LEN 4096
#define DM    1024
#define NHEAD 16
#define HDIM  64
#define C3    3072   // 3 * DM

typedef __attribute__((ext_vector_type(8))) short bf8_t;   // 8 bf16 (4 VGPR)
typedef __attribute__((ext_vector_type(4))) float f32x4;

__device__ __forceinline__ short f2bf(float f) {
    union { float f; unsigned u; } v; v.f = f;
    unsigned r = v.u + 0x7FFF + ((v.u >> 16) & 1);   // RNE, finite inputs
    return (short)(r >> 16);
}

// ---------------------------------------------------------------------------
// GEMM + bias, fp32 in / fp32 out.  BM=BN=128, BK=16, 256 thr, 8x8 microtile.
// ---------------------------------------------------------------------------
__global__ __launch_bounds__(256)
void gemm_bias_f32(const float* __restrict__ A, const float* __restrict__ B,
                   const float* __restrict__ bias, float* __restrict__ C,
                   int M, int N, int K)
{
    __shared__ float As[16][132];
    __shared__ float Bs[16][132];

    const int tid = threadIdx.x;
    const int tx  = tid & 15;
    const int ty  = tid >> 4;
    const int row0 = blockIdx.y * 128;
    const int col0 = blockIdx.x * 128;

    float acc[8][8];
    #pragma unroll
    for (int i = 0; i < 8; ++i)
        #pragma unroll
        for (int j = 0; j < 8; ++j) acc[i][j] = 0.f;

    const int lm  = tid >> 1;
    const int lk8 = (tid & 1) * 8;
    const int lkB = tid >> 4;
    const int lnB = (tid & 15) * 8;

    for (int k0 = 0; k0 < K; k0 += 16) {
        const float* ap = A + (size_t)(row0 + lm) * K + k0 + lk8;
        float4 a0 = *(const float4*)ap;
        float4 a1 = *(const float4*)(ap + 4);
        As[lk8 + 0][lm] = a0.x; As[lk8 + 1][lm] = a0.y;
        As[lk8 + 2][lm] = a0.z; As[lk8 + 3][lm] = a0.w;
        As[lk8 + 4][lm] = a1.x; As[lk8 + 5][lm] = a1.y;
        As[lk8 + 6][lm] = a1.z; As[lk8 + 7][lm] = a1.w;
        const float* bp = B + (size_t)(k0 + lkB) * N + col0 + lnB;
        *(float4*)&Bs[lkB][lnB]     = *(const float4*)bp;
        *(float4*)&Bs[lkB][lnB + 4] = *(const float4*)(bp + 4);
        __syncthreads();

        #pragma unroll
        for (int k = 0; k < 16; ++k) {
            float4 va0 = *(float4*)&As[k][ty * 8];
            float4 va1 = *(float4*)&As[k][ty * 8 + 4];
            float4 vb0 = *(float4*)&Bs[k][tx * 8];
            float4 vb1 = *(float4*)&Bs[k][tx * 8 + 4];
            float av[8] = {va0.x, va0.y, va0.z, va0.w, va1.x, va1.y, va1.z, va1.w};
            float bv[8] = {vb0.x, vb0.y, vb0.z, vb0.w, vb1.x, vb1.y, vb1.z, vb1.w};
            #pragma unroll
            for (int i = 0; i < 8; ++i)
                #pragma unroll
                for (int j = 0; j < 8; ++j)
                    acc[i][j] = fmaf(av[i], bv[j], acc[i][j]);
        }
        __syncthreads();
    }

    #pragma unroll
    for (int i = 0; i < 8; ++i) {
        const int row = row0 + ty * 8 + i;
        float* cp = C + (size_t)row * N + col0 + tx * 8;
        const float* bb = bias + col0 + tx * 8;
        float4 o0 = {acc[i][0] + bb[0], acc[i][1] + bb[1],
                     acc[i][2] + bb[2], acc[i][3] + bb[3]};
        float4 o1 = {acc[i][4] + bb[4], acc[i][5] + bb[5],
                     acc[i][6] + bb[6], acc[i][7] + bb[7]};
        *(float4*)cp       = o0;
        *(float4*)(cp + 4) = o1;
    }
}

// ---------------------------------------------------------------------------
// Same GEMM but epilogue casts to bf16 (for the QKV projection output).
// ---------------------------------------------------------------------------
__global__ __launch_bounds__(256)
void gemm_bias_f32_bf16out(const float* __restrict__ A, const float* __restrict__ B,
                           const float* __restrict__ bias, short* __restrict__ C,
                           int M, int N, int K)
{
    __shared__ float As[16][132];
    __shared__ float Bs[16][132];

    const int tid = threadIdx.x;
    const int tx  = tid & 15;
    const int ty  = tid >> 4;
    const int row0 = blockIdx.y * 128;
    const int col0 = blockIdx.x * 128;

    float acc[8][8];
    #pragma unroll
    for (int i = 0; i < 8; ++i)
        #pragma unroll
        for (int j = 0; j < 8; ++j) acc[i][j] = 0.f;

    const int lm  = tid >> 1;
    const int lk8 = (tid & 1) * 8;
    const int lkB = tid >> 4;
    const int lnB = (tid & 15) * 8;

    for (int k0 = 0; k0 < K; k0 += 16) {
        const float* ap = A + (size_t)(row0 + lm) * K + k0 + lk8;
        float4 a0 = *(const float4*)ap;
        float4 a1 = *(const float4*)(ap + 4);
        As[lk8 + 0][lm] = a0.x; As[lk8 + 1][lm] = a0.y;
        As[lk8 + 2][lm] = a0.z; As[lk8 + 3][lm] = a0.w;
        As[lk8 + 4][lm] = a1.x; As[lk8 + 5][lm] = a1.y;
        As[lk8 + 6][lm] = a1.z; As[lk8 + 7][lm] = a1.w;
        const float* bp = B + (size_t)(k0 + lkB) * N + col0 + lnB;
        *(float4*)&Bs[lkB][lnB]     = *(const float4*)bp;
        *(float4*)&Bs[lkB][lnB + 4] = *(const float4*)(bp + 4);
        __syncthreads();

        #pragma unroll
        for (int k = 0; k < 16; ++k) {
            float4 va0 = *(float4*)&As[k][ty * 8];
            float4 va1 = *(float4*)&As[k][ty * 8 + 4];
            float4 vb0 = *(float4*)&Bs[k][tx * 8];
            float4 vb1 = *(float4*)&Bs[k][tx * 8 + 4];
            float av[8] = {va0.x, va0.y, va0.z, va0.w, va1.x, va1.y, va1.z, va1.w};
            float bv[8] = {vb0.x, vb0.y, vb0.z, vb0.w, vb1.x, vb1.y, vb1.z, vb1.w};
            #pragma unroll
            for (int i = 0; i < 8; ++i)
                #pragma unroll
                for (int j = 0; j < 8; ++j)
                    acc[i][j] = fmaf(av[i], bv[j], acc[i][j]);
        }
        __syncthreads();
    }

    #pragma unroll
    for (int i = 0; i < 8; ++i) {
        const int row = row0 + ty * 8 + i;
        short* cp = C + (size_t)row * N + col0 + tx * 8;
        const float* bb = bias + col0 + tx * 8;
        bf8_t ov;
        #pragma unroll
        for (int j = 0; j < 8; ++j) ov[j] = f2bf(acc[i][j] + bb[j]);
        *(bf8_t*)cp = ov;
    }
}

// ---------------------------------------------------------------------------
// Flash attention, bf16 MFMA (16x16x32), fp32 accumulate.
// qkv (bf16): [8192, 3072], col = which*1024 + h*64 + d
// out (fp32): [8192, 1024] in [b, s, h, hd] layout
// Block: 256 thr = 4 waves; QBLK=64 (wave w owns q-rows w*16..w*16+15); KBLK=64.
// ---------------------------------------------------------------------------
__global__ __launch_bounds__(256)
void attn_mfma_bf16(const short* __restrict__ qkv, float* __restrict__ out)
{
    const int qt   = blockIdx.x;
    const int bh   = blockIdx.y;
    const int b    = bh >> 4;
    const int h    = bh & 15;
    const int tid  = threadIdx.x;
    const int lane = tid & 63;
    const int w    = tid >> 6;      // wave 0..3
    const int l15  = lane & 15;
    const int l4   = lane >> 4;     // 0..3

    // K: row-major [64][64], XOR-swizzled (byte ^= (row&7)<<4)
    // Vt: transposed [d=64][k=64], same swizzle
    // Ps: per-wave P tile [16 rows][stride 72]
    __shared__ __align__(16) short Ks[64 * 64];
    __shared__ __align__(16) short Vt[64 * 64];
    __shared__ __align__(16) short Ps[4][16 * 72];

    const float scale = 0.125f;     // 1/sqrt(64)
    const float NEG   = -1e30f;

    const short* base = qkv + (size_t)b * S_LEN * C3 + h * HDIM;

    // ---- Q fragments in registers (A-layout: row=l15, k-slice=l4) ----
    const int q0 = qt * 64 + w * 16;
    bf8_t qA[2];
    {
        const short* qp = base + (size_t)(q0 + l15) * C3 + l4 * 8;
        qA[0] = *(const bf8_t*)(qp);
        qA[1] = *(const bf8_t*)(qp + 32);
    }

    float m_r[4], l_r[4];
    f32x4 o4[4];
    #pragma unroll
    for (int r = 0; r < 4; ++r) { m_r[r] = -INFINITY; l_r[r] = 0.f; }
    #pragma unroll
    for (int dt = 0; dt < 4; ++dt) o4[dt] = (f32x4){0.f, 0.f, 0.f, 0.f};

    const int krow = tid & 63;           // staging: row handled by this thread
    const int d0   = (tid >> 6) * 16;    // staging: d-offset (16 elems)

    for (int kt = 0; kt <= qt; ++kt) {
        __syncthreads();   // previous iteration finished reading Ks/Vt

        // ---- stage K (row-major swizzled) and V (transposed swizzled) ----
        {
            const short* kp = base + (size_t)(kt * 64 + krow) * C3 + DM + d0;
            bf8_t kv0 = *(const bf8_t*)kp;
            bf8_t kv1 = *(const bf8_t*)(kp + 8);
            const short* vp = kp + DM;
            bf8_t vv0 = *(const bf8_t*)vp;
            bf8_t vv1 = *(const bf8_t*)(vp + 8);

            int offK0 = (krow * 128 + d0 * 2) ^ ((krow & 7) << 4);
            int offK1 = (krow * 128 + (d0 + 8) * 2) ^ ((krow & 7) << 4);
            *(bf8_t*)((char*)Ks + offK0) = kv0;
            *(bf8_t*)((char*)Ks + offK1) = kv1;

            #pragma unroll
            for (int dd = 0; dd < 8; ++dd) {
                int d = d0 + dd;
                int off = (d * 128 + krow * 2) ^ ((d & 7) << 4);
                *(short*)((char*)Vt + off) = vv0[dd];
            }
            #pragma unroll
            for (int dd = 8; dd < 16; ++dd) {
                int d = d0 + dd;
                int off = (d * 128 + krow * 2) ^ ((d & 7) << 4);
                *(short*)((char*)Vt + off) = vv1[dd - 8];
            }
        }
        __syncthreads();

        // diagonal block: wave w only needs k-tiles 0..w
        const int nkt = (kt < qt) ? 4 : (w + 1);

        // ---- S = Q K^T (per wave: 16 q-rows x 64 k-cols) ----
        f32x4 s4[4];
        #pragma unroll
        for (int ktile = 0; ktile < 4; ++ktile) {
            if (ktile < nkt) {
                f32x4 acc = (f32x4){0.f, 0.f, 0.f, 0.f};
                #pragma unroll
                for (int s = 0; s < 2; ++s) {
                    int row = ktile * 16 + l15;
                    int off = (row * 128 + (s * 32 + l4 * 8) * 2) ^ ((row & 7) << 4);
                    bf8_t kB = *(bf8_t*)((char*)Ks + off);
                    acc = __builtin_amdgcn_mfma_f32_16x16x32_bf16(qA[s], kB, acc, 0, 0, 0);
                }
                #pragma unroll
                for (int r = 0; r < 4; ++r) acc[r] *= scale;
                if (kt == qt && ktile == w) {
                    #pragma unroll
                    for (int r = 0; r < 4; ++r)
                        if (l15 > l4 * 4 + r) acc[r] = NEG;
                }
                s4[ktile] = acc;
            } else {
                s4[ktile] = (f32x4){NEG, NEG, NEG, NEG};
            }
        }

        // ---- online softmax (row r lives on 16 lanes sharing l4-group) ----
        float tmax[4];
        #pragma unroll
        for (int r = 0; r < 4; ++r)
            tmax[r] = fmaxf(fmaxf(s4[0][r], s4[1][r]), fmaxf(s4[2][r], s4[3][r]));
        #pragma unroll
        for (int off = 1; off < 16; off <<= 1)
            #pragma unroll
            for (int r = 0; r < 4; ++r)
                tmax[r] = fmaxf(tmax[r], __shfl_xor(tmax[r], off));

        float p[4][4], alpha[4], rsum[4];
        #pragma unroll
        for (int r = 0; r < 4; ++r) {
            const float nm = fmaxf(m_r[r], tmax[r]);
            alpha[r] = __expf(m_r[r] - nm);
            m_r[r] = nm;
            #pragma unroll
            for (int ktile = 0; ktile < 4; ++ktile)
                p[ktile][r] = __expf(s4[ktile][r] - nm);
            rsum[r] = (p[0][r] + p[1][r]) + (p[2][r] + p[3][r]);
        }
        #pragma unroll
        for (int off = 1; off < 16; off <<= 1)
            #pragma unroll
            for (int r = 0; r < 4; ++r)
                rsum[r] += __shfl_xor(rsum[r], off);
        #pragma unroll
        for (int r = 0; r < 4; ++r) {
            l_r[r] = alpha[r] * l_r[r] + rsum[r];
            #pragma unroll
            for (int dt = 0; dt < 4; ++dt) o4[dt][r] *= alpha[r];
        }

        // ---- P -> per-wave LDS (bf16), D-layout rows -> A-layout rows ----
        #pragma unroll
        for (int ktile = 0; ktile < 4; ++ktile)
            #pragma unroll
            for (int r = 0; r < 4; ++r)
                Ps[w][(l4 * 4 + r) * 72 + ktile * 16 + l15] = f2bf(p[ktile][r]);

        // wave-local LDS RAW fence (rule 18)
        __asm__ volatile("s_waitcnt lgkmcnt(0)" ::: "memory");
        __builtin_amdgcn_sched_barrier(0);

        // ---- O += P V ----
        bf8_t pA[2];
        #pragma unroll
        for (int ks = 0; ks < 2; ++ks)
            pA[ks] = *(bf8_t*)((char*)&Ps[w][0] + l15 * 144 + (ks * 32 + l4 * 8) * 2);

        #pragma unroll
        for (int dt = 0; dt < 4; ++dt) {
            #pragma unroll
            for (int ks = 0; ks < 2; ++ks) {
                int d = dt * 16 + l15;
                int off = (d * 128 + (ks * 32 + l4 * 8) * 2) ^ ((d & 7) << 4);
                bf8_t vB = *(bf8_t*)((char*)Vt + off);
                o4[dt] = __builtin_amdgcn_mfma_f32_16x16x32_bf16(pA[ks], vB, o4[dt], 0, 0, 0);
            }
        }
    }

    // ---- epilogue: normalize, store fp32 to [b, s, h, hd] ----
    float inv[4];
    #pragma unroll
    for (int r = 0; r < 4; ++r) inv[r] = 1.f / l_r[r];
    #pragma unroll
    for (int dt = 0; dt < 4; ++dt)
        #pragma unroll
        for (int r = 0; r < 4; ++r) {
            const int row = q0 + l4 * 4 + r;
            out[(size_t)(b * S_LEN + row) * DM + h * HDIM + dt * 16 + l15] =
                o4[dt][r] * inv[r];
        }
}

// ---------------------------------------------------------------------------
extern "C" void kernel_launch(void* const* d_in, const int* in_sizes, int n_in,
                              void* d_out, int out_size, void* d_ws, size_t ws_size,
                              hipStream_t stream)
{
    const float* x     = (const float*)d_in[0];
    const float* w_qkv = (const float*)d_in[1];
    const float* b_qkv = (const float*)d_in[2];
    const float* w_out = (const float*)d_in[3];
    const float* b_out = (const float*)d_in[4];
    float* out = (float*)d_out;

    const int M = 2 * S_LEN;   // 8192 tokens

    short* qkvb = (short*)d_ws;                               // bf16 [8192,3072] 50.3MB
    float* attn = (float*)((char*)d_ws + (size_t)M * C3 * 2); // fp32 [8192,1024] 33.5MB

    // 1) QKV projection -> bf16
    gemm_bias_f32_bf16out<<<dim3(C3 / 128, M / 128), 256, 0, stream>>>(
        x, w_qkv, b_qkv, qkvb, M, C3, DM);

    // 2) causal flash attention (bf16 MFMA) -> fp32 attn
    attn_mfma_bf16<<<dim3(S_LEN / 64, 2 * NHEAD), 256, 0, stream>>>(qkvb, attn);

    // 3) output projection (fp32)
    gemm_bias_f32<<<dim3(DM / 128, M / 128), 256, 0, stream>>>(
        attn, w_out, b_out, out, M, DM, DM);
}

// Round 3
// 517.129 us; speedup vs baseline: 4.6977x; 2.3011x over previous
//
#include <hip/hip_runtime.h>
#include <math.h>

#define S_LEN 4096
#define DM    1024
#define NHEAD 16
#define HDIM  64
#define C3    3072   // 3 * DM

typedef __attribute__((ext_vector_type(8))) short bf8_t;   // 8 bf16
typedef __attribute__((ext_vector_type(4))) float f32x4;

__device__ __forceinline__ short f2bf(float f) {
    union { float f; unsigned u; } v; v.f = f;
    unsigned r = v.u + 0x7FFF + ((v.u >> 16) & 1);   // RNE, finite inputs
    return (short)(r >> 16);
}

__device__ __forceinline__ void gload_lds16(const void* g, void* l) {
    __builtin_amdgcn_global_load_lds(
        (const __attribute__((address_space(1))) unsigned int*)g,
        (__attribute__((address_space(3))) unsigned int*)l, 16, 0, 0);
}

// ---------------------------------------------------------------------------
// Elementwise fp32 -> bf16 cast (8 elems/thread).
// ---------------------------------------------------------------------------
__global__ void cast_f32_bf16(const float* __restrict__ in, short* __restrict__ out, int n8)
{
    int i = blockIdx.x * blockDim.x + threadIdx.x;
    if (i < n8) {
        float4 a = ((const float4*)in)[i * 2];
        float4 b = ((const float4*)in)[i * 2 + 1];
        bf8_t v = {f2bf(a.x), f2bf(a.y), f2bf(a.z), f2bf(a.w),
                   f2bf(b.x), f2bf(b.y), f2bf(b.z), f2bf(b.w)};
        ((bf8_t*)out)[i] = v;
    }
}

// ---------------------------------------------------------------------------
// Transpose + cast: in [R][C] fp32 -> out [C][R] bf16.  32x32 tiles.
// ---------------------------------------------------------------------------
__global__ __launch_bounds__(256)
void transpose_cast(const float* __restrict__ in, short* __restrict__ out, int R, int C)
{
    __shared__ float t[32][33];
    const int tx = threadIdx.x & 31;
    const int ty = threadIdx.x >> 5;      // 0..7
    const int r0 = blockIdx.y * 32;
    const int c0 = blockIdx.x * 32;
    #pragma unroll
    for (int i = 0; i < 32; i += 8)
        t[ty + i][tx] = in[(size_t)(r0 + ty + i) * C + c0 + tx];
    __syncthreads();
    #pragma unroll
    for (int i = 0; i < 32; i += 8)
        out[(size_t)(c0 + ty + i) * R + r0 + tx] = f2bf(t[tx][ty + i]);
}

// ---------------------------------------------------------------------------
// bf16 MFMA GEMM: C[M,N] = A[M,K] @ Bt[N,K]^T + bias.
// m97 structure: 128x128 tile, BK=64, 256 thr (4 waves, 2x2), 16x16x32 MFMA,
// global_load_lds w/ pre-swizzled source (XOR (row&7)<<4), 2-barrier K-loop.
// Requires K==1024, M%128==0, N%128==0, grid = (M/128)*(N/128), %8==0.
// ---------------------------------------------------------------------------
template<bool BF16OUT>
__global__ __launch_bounds__(256)
void gemm_mfma(const short* __restrict__ A, const short* __restrict__ Bt,
               const float* __restrict__ bias, void* __restrict__ Cout,
               int M, int N)
{
    constexpr int K = 1024;
    __shared__ __align__(16) short As[128 * 64];
    __shared__ __align__(16) short Bs[128 * 64];

    const int nbx = N / 128;
    const int nwg = (M / 128) * nbx;
    int bid = blockIdx.x;
    bid = (bid & 7) * (nwg >> 3) + (bid >> 3);      // XCD-aware (nwg%8==0)
    const int by = bid / nbx, bx = bid % nbx;
    const int row0 = by * 128, col0 = bx * 128;

    const int tid  = threadIdx.x;
    const int lane = tid & 63;
    const int w    = tid >> 6;
    const int l15  = lane & 15;
    const int l4   = lane >> 4;
    const int wr   = w >> 1, wc = w & 1;

    f32x4 acc[4][4];
    #pragma unroll
    for (int i = 0; i < 4; ++i)
        #pragma unroll
        for (int j = 0; j < 4; ++j) acc[i][j] = (f32x4){0.f, 0.f, 0.f, 0.f};

    // staging: 16 instructions x 1KB = 16KB per tile; this thread's 4 chunks
    size_t goff[4];  // global byte offset rel. to (tile base + k0)
    int    loff[4];  // linear LDS byte offset
    #pragma unroll
    for (int i = 0; i < 4; ++i) {
        const int o   = (w * 4 + i) * 1024 + lane * 16;
        const int row = o >> 7;
        const int col = (o & 127) ^ ((row & 7) << 4);   // inverse-swizzle source
        goff[i] = (size_t)row * (K * 2) + col;
        loff[i] = o;
    }
    const char* Ab = (const char*)A  + (size_t)row0 * (K * 2);
    const char* Bb = (const char*)Bt + (size_t)col0 * (K * 2);

    for (int k0 = 0; k0 < K; k0 += 64) {
        __syncthreads();   // previous compute done reading LDS
        #pragma unroll
        for (int i = 0; i < 4; ++i) {
            gload_lds16(Ab + goff[i] + k0 * 2, (char*)As + loff[i]);
            gload_lds16(Bb + goff[i] + k0 * 2, (char*)Bs + loff[i]);
        }
        __syncthreads();   // drains vmcnt before compute

        #pragma unroll
        for (int ks = 0; ks < 2; ++ks) {
            bf8_t af[4], bfr[4];
            #pragma unroll
            for (int mi = 0; mi < 4; ++mi) {
                const int row = wr * 64 + mi * 16 + l15;
                const int off = (row * 128 + ks * 64 + l4 * 16) ^ ((row & 7) << 4);
                af[mi] = *(bf8_t*)((char*)As + off);
            }
            #pragma unroll
            for (int ni = 0; ni < 4; ++ni) {
                const int row = wc * 64 + ni * 16 + l15;
                const int off = (row * 128 + ks * 64 + l4 * 16) ^ ((row & 7) << 4);
                bfr[ni] = *(bf8_t*)((char*)Bs + off);
            }
            #pragma unroll
            for (int mi = 0; mi < 4; ++mi)
                #pragma unroll
                for (int ni = 0; ni < 4; ++ni)
                    acc[mi][ni] = __builtin_amdgcn_mfma_f32_16x16x32_bf16(
                        af[mi], bfr[ni], acc[mi][ni], 0, 0, 0);
        }
    }

    // epilogue: + bias, store
    float bv[4];
    #pragma unroll
    for (int ni = 0; ni < 4; ++ni)
        bv[ni] = bias[col0 + wc * 64 + ni * 16 + l15];

    #pragma unroll
    for (int mi = 0; mi < 4; ++mi)
        #pragma unroll
        for (int r = 0; r < 4; ++r) {
            const int row = row0 + wr * 64 + mi * 16 + l4 * 4 + r;
            #pragma unroll
            for (int ni = 0; ni < 4; ++ni) {
                const int col = col0 + wc * 64 + ni * 16 + l15;
                const float val = acc[mi][ni][r] + bv[ni];
                if constexpr (BF16OUT)
                    ((short*)Cout)[(size_t)row * N + col] = f2bf(val);
                else
                    ((float*)Cout)[(size_t)row * N + col] = val;
            }
        }
}

// ---------------------------------------------------------------------------
// Flash attention, bf16 MFMA (16x16x32), fp32 accumulate, bf16 out.
// qkv (bf16): [8192, 3072], col = which*1024 + h*64 + d
// out (bf16): [8192, 1024] in [b, s, h, hd] layout
// ---------------------------------------------------------------------------
__global__ __launch_bounds__(256)
void attn_mfma_bf16(const short* __restrict__ qkv, short* __restrict__ out)
{
    const int qt   = blockIdx.x;
    const int bh   = blockIdx.y;
    const int b    = bh >> 4;
    const int h    = bh & 15;
    const int tid  = threadIdx.x;
    const int lane = tid & 63;
    const int w    = tid >> 6;
    const int l15  = lane & 15;
    const int l4   = lane >> 4;

    __shared__ __align__(16) short Ks[64 * 64];
    __shared__ __align__(16) short Vt[64 * 64];
    __shared__ __align__(16) short Ps[4][16 * 72];

    const float scale = 0.125f;
    const float NEG   = -1e30f;

    const short* base = qkv + (size_t)b * S_LEN * C3 + h * HDIM;

    const int q0 = qt * 64 + w * 16;
    bf8_t qA[2];
    {
        const short* qp = base + (size_t)(q0 + l15) * C3 + l4 * 8;
        qA[0] = *(const bf8_t*)(qp);
        qA[1] = *(const bf8_t*)(qp + 32);
    }

    float m_r[4], l_r[4];
    f32x4 o4[4];
    #pragma unroll
    for (int r = 0; r < 4; ++r) { m_r[r] = -INFINITY; l_r[r] = 0.f; }
    #pragma unroll
    for (int dt = 0; dt < 4; ++dt) o4[dt] = (f32x4){0.f, 0.f, 0.f, 0.f};

    const int krow = tid & 63;
    const int d0   = (tid >> 6) * 16;

    for (int kt = 0; kt <= qt; ++kt) {
        __syncthreads();

        {
            const short* kp = base + (size_t)(kt * 64 + krow) * C3 + DM + d0;
            bf8_t kv0 = *(const bf8_t*)kp;
            bf8_t kv1 = *(const bf8_t*)(kp + 8);
            const short* vp = kp + DM;
            bf8_t vv0 = *(const bf8_t*)vp;
            bf8_t vv1 = *(const bf8_t*)(vp + 8);

            int offK0 = (krow * 128 + d0 * 2) ^ ((krow & 7) << 4);
            int offK1 = (krow * 128 + (d0 + 8) * 2) ^ ((krow & 7) << 4);
            *(bf8_t*)((char*)Ks + offK0) = kv0;
            *(bf8_t*)((char*)Ks + offK1) = kv1;

            #pragma unroll
            for (int dd = 0; dd < 8; ++dd) {
                int d = d0 + dd;
                int off = (d * 128 + krow * 2) ^ ((d & 7) << 4);
                *(short*)((char*)Vt + off) = vv0[dd];
            }
            #pragma unroll
            for (int dd = 8; dd < 16; ++dd) {
                int d = d0 + dd;
                int off = (d * 128 + krow * 2) ^ ((d & 7) << 4);
                *(short*)((char*)Vt + off) = vv1[dd - 8];
            }
        }
        __syncthreads();

        const int nkt = (kt < qt) ? 4 : (w + 1);

        f32x4 s4[4];
        #pragma unroll
        for (int ktile = 0; ktile < 4; ++ktile) {
            if (ktile < nkt) {
                f32x4 acc = (f32x4){0.f, 0.f, 0.f, 0.f};
                #pragma unroll
                for (int s = 0; s < 2; ++s) {
                    int row = ktile * 16 + l15;
                    int off = (row * 128 + (s * 32 + l4 * 8) * 2) ^ ((row & 7) << 4);
                    bf8_t kB = *(bf8_t*)((char*)Ks + off);
                    acc = __builtin_amdgcn_mfma_f32_16x16x32_bf16(qA[s], kB, acc, 0, 0, 0);
                }
                #pragma unroll
                for (int r = 0; r < 4; ++r) acc[r] *= scale;
                if (kt == qt && ktile == w) {
                    #pragma unroll
                    for (int r = 0; r < 4; ++r)
                        if (l15 > l4 * 4 + r) acc[r] = NEG;
                }
                s4[ktile] = acc;
            } else {
                s4[ktile] = (f32x4){NEG, NEG, NEG, NEG};
            }
        }

        float tmax[4];
        #pragma unroll
        for (int r = 0; r < 4; ++r)
            tmax[r] = fmaxf(fmaxf(s4[0][r], s4[1][r]), fmaxf(s4[2][r], s4[3][r]));
        #pragma unroll
        for (int off = 1; off < 16; off <<= 1)
            #pragma unroll
            for (int r = 0; r < 4; ++r)
                tmax[r] = fmaxf(tmax[r], __shfl_xor(tmax[r], off));

        float p[4][4], alpha[4], rsum[4];
        #pragma unroll
        for (int r = 0; r < 4; ++r) {
            const float nm = fmaxf(m_r[r], tmax[r]);
            alpha[r] = __expf(m_r[r] - nm);
            m_r[r] = nm;
            #pragma unroll
            for (int ktile = 0; ktile < 4; ++ktile)
                p[ktile][r] = __expf(s4[ktile][r] - nm);
            rsum[r] = (p[0][r] + p[1][r]) + (p[2][r] + p[3][r]);
        }
        #pragma unroll
        for (int off = 1; off < 16; off <<= 1)
            #pragma unroll
            for (int r = 0; r < 4; ++r)
                rsum[r] += __shfl_xor(rsum[r], off);
        #pragma unroll
        for (int r = 0; r < 4; ++r) {
            l_r[r] = alpha[r] * l_r[r] + rsum[r];
            #pragma unroll
            for (int dt = 0; dt < 4; ++dt) o4[dt][r] *= alpha[r];
        }

        #pragma unroll
        for (int ktile = 0; ktile < 4; ++ktile)
            #pragma unroll
            for (int r = 0; r < 4; ++r)
                Ps[w][(l4 * 4 + r) * 72 + ktile * 16 + l15] = f2bf(p[ktile][r]);

        __asm__ volatile("s_waitcnt lgkmcnt(0)" ::: "memory");
        __builtin_amdgcn_sched_barrier(0);

        bf8_t pA[2];
        #pragma unroll
        for (int ks = 0; ks < 2; ++ks)
            pA[ks] = *(bf8_t*)((char*)&Ps[w][0] + l15 * 144 + (ks * 32 + l4 * 8) * 2);

        #pragma unroll
        for (int dt = 0; dt < 4; ++dt) {
            #pragma unroll
            for (int ks = 0; ks < 2; ++ks) {
                int d = dt * 16 + l15;
                int off = (d * 128 + (ks * 32 + l4 * 8) * 2) ^ ((d & 7) << 4);
                bf8_t vB = *(bf8_t*)((char*)Vt + off);
                o4[dt] = __builtin_amdgcn_mfma_f32_16x16x32_bf16(pA[ks], vB, o4[dt], 0, 0, 0);
            }
        }
    }

    float inv[4];
    #pragma unroll
    for (int r = 0; r < 4; ++r) inv[r] = 1.f / l_r[r];
    #pragma unroll
    for (int dt = 0; dt < 4; ++dt)
        #pragma unroll
        for (int r = 0; r < 4; ++r) {
            const int row = q0 + l4 * 4 + r;
            out[(size_t)(b * S_LEN + row) * DM + h * HDIM + dt * 16 + l15] =
                f2bf(o4[dt][r] * inv[r]);
        }
}

// ---------------------------------------------------------------------------
extern "C" void kernel_launch(void* const* d_in, const int* in_sizes, int n_in,
                              void* d_out, int out_size, void* d_ws, size_t ws_size,
                              hipStream_t stream)
{
    const float* x     = (const float*)d_in[0];
    const float* w_qkv = (const float*)d_in[1];
    const float* b_qkv = (const float*)d_in[2];
    const float* w_out = (const float*)d_in[3];
    const float* b_out = (const float*)d_in[4];
    float* out = (float*)d_out;

    const int M = 2 * S_LEN;   // 8192 tokens

    char* ws = (char*)d_ws;
    short* qkvb  = (short*)(ws);                    // [8192,3072] bf16  50.3MB
    short* attnb = (short*)(ws + 50331648);         // [8192,1024] bf16  16.8MB
    short* xb    = (short*)(ws + 67108864);         // [8192,1024] bf16  16.8MB
    short* wqkvT = (short*)(ws + 83886080);         // [3072,1024] bf16   6.3MB
    short* woutT = (short*)(ws + 90177536);         // [1024,1024] bf16   2.1MB

    // 0) casts / transposes to bf16
    cast_f32_bf16<<<dim3((M * DM / 8 + 255) / 256), 256, 0, stream>>>(x, xb, M * DM / 8);
    transpose_cast<<<dim3(C3 / 32, DM / 32), 256, 0, stream>>>(w_qkv, wqkvT, DM, C3);
    transpose_cast<<<dim3(DM / 32, DM / 32), 256, 0, stream>>>(w_out, woutT, DM, DM);

    // 1) QKV projection (bf16 MFMA) -> bf16
    gemm_mfma<true><<<dim3((M / 128) * (C3 / 128)), 256, 0, stream>>>(
        xb, wqkvT, b_qkv, qkvb, M, C3);

    // 2) causal flash attention (bf16 MFMA) -> bf16
    attn_mfma_bf16<<<dim3(S_LEN / 64, 2 * NHEAD), 256, 0, stream>>>(qkvb, attnb);

    // 3) output projection (bf16 MFMA) -> fp32
    gemm_mfma<false><<<dim3((M / 128) * (DM / 128)), 256, 0, stream>>>(
        attnb, woutT, b_out, out, M, DM);
}